// Round 12
// baseline (161.471 us; speedup 1.0000x reference)
//
#include <hip/hip_runtime.h>

typedef _Float16 half_t;
typedef _Float16 half8 __attribute__((ext_vector_type(8)));
typedef _Float16 half4 __attribute__((ext_vector_type(4)));
typedef float floatx4 __attribute__((ext_vector_type(4)));
typedef float floatx16 __attribute__((ext_vector_type(16)));

#define C1 0.72134752044448170368f   /* 2*log2(e)/SCALE, SCALE=4 */
#define C2 14.4269504088896340736f   /* 10*log2(e) */
#define C3 28.8539008177792681472f   /* 20*log2(e) */

__device__ __forceinline__ floatx4 zero4() {
    floatx4 z; z[0] = z[1] = z[2] = z[3] = 0.f; return z;
}
__device__ __forceinline__ floatx16 zero16() {
    floatx16 z;
#pragma unroll
    for (int i = 0; i < 16; ++i) z[i] = 0.f;
    return z;
}

// p = exp(10*tanh(s)) computed as exp2(b - C3 * rcp(exp2(S') + 1)),
// S' = 2*log2e*s (folded into Wq), b = C2 (live slot) or -1e30 (pad -> p=0).
// Validated issue-port model (fits R8 to 0.3%): trans ~8 issue cyc, VALU ~2.
// This 3-trans + 2-VALU mix is the proven floor (R4/R8 both directions).
__device__ __forceinline__ float pfun(float sp, float b) {
    float u = __builtin_amdgcn_exp2f(sp);
    float r = __builtin_amdgcn_rcpf(u + 1.0f);
    return __builtin_amdgcn_exp2f(b - C3 * r);
}

// ---------------- k1: QKV projections + weight conversion + K/V COMPACTION -
// R11 proved per-launch overhead ~10 us; weight conversion stays fused here.
// NEW (R12): since masked keys have p == 0 EXACTLY in the reference
// (exp(-1e10) underflows), K and V^T are written COMPACTED to the unmasked
// slots of each bc (prefix-sum via wave ballots -- every block spans one bc).
// Pad slots [cnt, ceil32(cnt)) are zero-filled (NaN-safe vs poisoned ws);
// attn then iterates ceil(cnt/32) ~= 14 of 16 tiles: ~12.5% less issue-port
// demand on the saturated trans/VALU pipes. Q is NOT compacted (all queries
// produce output). Attention is permutation-invariant over keys -> exact.
__global__ __launch_bounds__(256) void k_proj(
        const float* __restrict__ Q, const float* __restrict__ K,
        const float* __restrict__ V, const int* __restrict__ mask,
        const float* __restrict__ Wq, const float* __restrict__ Wk,
        const float* __restrict__ Wv, const float* __restrict__ Wo,
        half_t* __restrict__ qw, half_t* __restrict__ kw, half_t* __restrict__ vw,
        half_t* __restrict__ Who) {
    int which = blockIdx.y;
    int tid = threadIdx.x;

    if (which == 3) {
        // Wo fp32 -> fp16, 64 active blocks x 256 threads = 16384 elems
        int bx = blockIdx.x;
        if (bx < 64) {
            int idx = bx * 256 + tid;
            Who[idx] = (half_t)Wo[idx];
        }
        return;
    }

    __shared__ half_t Wl[128 * 136];         // padded [f][e] panel, 34.8 KB
    __shared__ unsigned long long cwv[8];    // per-64-token "unmasked" bitmask
    __shared__ int wps[9];                   // word prefix counts; wps[8]=cnt

    const float* X    = (which == 0) ? Q  : (which == 1) ? K  : V;
    const float* Wsrc = (which == 0) ? Wq : (which == 1) ? Wk : Wv;
    float scale = (which == 0) ? C1 : 1.0f;

    int bxx = blockIdx.x;
    int bc = bxx >> 3;                       // block spans one bc (64 tokens)
    int w = tid >> 6, lane = tid & 63;

    // ---- mask bitmaps for K/V compaction (wave ballots) ----
    if (which != 0) {
        int m0 = mask[bc * 512 + tid];
        int m1 = mask[bc * 512 + 256 + tid];
        unsigned long long b0 = __ballot(m0 == 0);   // chunk w
        unsigned long long b1 = __ballot(m1 == 0);   // chunk 4+w
        if (lane == 0) { cwv[w] = b0; cwv[4 + w] = b1; }
    }

    // ---- convert 16384 f32 weights -> fp16 into padded LDS ----
#pragma unroll
    for (int i = 0; i < 16; ++i) {
        int gidx = i * 1024 + tid * 4;
        float4 v = *(const float4*)(Wsrc + gidx);
        int f = gidx >> 7, e = gidx & 127;
        half4 hv;
        hv[0] = (half_t)(v.x * scale); hv[1] = (half_t)(v.y * scale);
        hv[2] = (half_t)(v.z * scale); hv[3] = (half_t)(v.w * scale);
        *(half4*)(Wl + f * 136 + e) = hv;
    }
    __syncthreads();

    if (which != 0 && tid == 0) {
        int acc = 0;
#pragma unroll
        for (int j = 0; j < 8; ++j) { wps[j] = acc; acc += __popcll(cwv[j]); }
        wps[8] = acc;
    }
    if (which != 0) __syncthreads();

    // ---- zero-fill pad slots [cnt, ceil32(cnt)) -- last block of each bc ----
    if (which != 0 && (bxx & 7) == 7) {
        int cnt = wps[8];
        int pad = (((cnt + 31) >> 5) << 5) - cnt;    // 0..31
        if (which == 1) {
            half8 z8;
#pragma unroll
            for (int j = 0; j < 8; ++j) z8[j] = (half_t)0.f;
            // kw layout (bc, h, n, 16): 8h x pad x 16 halves = 2 half8/slot
            for (int u = tid; u < 8 * 64; u += 256) {
                int nt = u >> 6, rem = u & 63;
                int p = rem >> 1, off = (rem & 1) * 8;
                if (p < pad)
                    *(half8*)(kw + (((bc * 8 + nt) * 512) + cnt + p) * 16 + off) = z8;
            }
        } else {
            // vw layout (bc, h, d, n): 128 rows x pad scalar halves
            for (int u = tid; u < 128 * 32; u += 256) {
                int r = u >> 5, p = u & 31;
                if (p < pad)
                    vw[(bc * 128 + r) * 512 + cnt + p] = (half_t)0.f;
            }
        }
    }

    int l15 = lane & 15, quad = lane >> 4;
    int tokbase = bxx * 64 + w * 16;

    floatx4 acc[8];
#pragma unroll
    for (int nt = 0; nt < 8; ++nt) acc[nt] = zero4();

#pragma unroll
    for (int ks = 0; ks < 4; ++ks) {
        const float* ap = X + (tokbase + l15) * 128 + ks * 32 + quad * 8;
        float4 a0 = *(const float4*)ap;
        float4 a1 = *(const float4*)(ap + 4);
        half8 xf;
        xf[0] = (half_t)a0.x; xf[1] = (half_t)a0.y; xf[2] = (half_t)a0.z; xf[3] = (half_t)a0.w;
        xf[4] = (half_t)a1.x; xf[5] = (half_t)a1.y; xf[6] = (half_t)a1.z; xf[7] = (half_t)a1.w;
        if (which == 2) {
#pragma unroll
            for (int nt = 0; nt < 8; ++nt) {
                half8 wf = *(const half8*)(Wl + (nt * 16 + l15) * 136 + ks * 32 + quad * 8);
                acc[nt] = __builtin_amdgcn_mfma_f32_16x16x32_f16(xf, wf, acc[nt], 0, 0, 0);
            }
        } else {
#pragma unroll
            for (int nt = 0; nt < 8; ++nt) {
                half8 wf = *(const half8*)(Wl + (nt * 16 + l15) * 136 + ks * 32 + quad * 8);
                acc[nt] = __builtin_amdgcn_mfma_f32_16x16x32_f16(wf, xf, acc[nt], 0, 0, 0);
            }
        }
    }

    if (which == 2) {
        // V: D[token = quad*4+r][f = l15] -> transposed COMPACTED store
        int n0 = (tokbase & 511) + quad * 4;
        int s_r[4]; bool keep_r[4];
#pragma unroll
        for (int r = 0; r < 4; ++r) {
            int n = n0 + r;
            unsigned long long cword = cwv[n >> 6];
            keep_r[r] = (cword >> (n & 63)) & 1ull;
            s_r[r] = wps[n >> 6] + __popcll(cword & ((1ull << (n & 63)) - 1ull));
        }
#pragma unroll
        for (int nt = 0; nt < 8; ++nt) {
#pragma unroll
            for (int r = 0; r < 4; ++r) {
                if (keep_r[r])
                    vw[((bc * 8 + nt) * 16 + l15) * 512 + s_r[r]] = (half_t)acc[nt][r];
            }
        }
    } else if (which == 1) {
        // K: D[f = quad*4+r][token = l15] -> COMPACTED store (bc, h, s, 16)
        int n = (tokbase & 511) + l15;
        unsigned long long cword = cwv[n >> 6];
        bool keep = (cword >> (n & 63)) & 1ull;
        int s = wps[n >> 6] + __popcll(cword & ((1ull << (n & 63)) - 1ull));
        if (keep) {
#pragma unroll
            for (int nt = 0; nt < 8; ++nt) {
                half4 hv;
                hv[0] = (half_t)acc[nt][0]; hv[1] = (half_t)acc[nt][1];
                hv[2] = (half_t)acc[nt][2]; hv[3] = (half_t)acc[nt][3];
                *(half4*)(kw + ((bc * 8 + nt) * 512 + s) * 16 + quad * 4) = hv;
            }
        }
    } else {
        // Q: D[f = quad*4+r][token = l15]; store (bc, h, n, 16) -- NOT compacted
        int R = tokbase + l15;
        int n = R & 511;
#pragma unroll
        for (int nt = 0; nt < 8; ++nt) {
            half4 hv;
            hv[0] = (half_t)acc[nt][0]; hv[1] = (half_t)acc[nt][1];
            hv[2] = (half_t)acc[nt][2]; hv[3] = (half_t)acc[nt][3];
            *(half4*)(qw + ((bc * 8 + nt) * 512 + n) * 16 + quad * 4) = hv;
        }
    }
}

// ---------------- k2: fused attention + output projection ------------------
// R5 configuration (proven best) + COMPACTED K/V: the c-loop runs
// NT = ceil(cnt/32) tiles (~14 of 16). bias is by compacted slot:
// slot < cnt -> C2 (all live slots are unmasked by construction),
// slot >= cnt -> -1e30 (zero-filled pads -> p = 0 exactly).
__global__ __launch_bounds__(512, 4) void k_attn_out(
        const half_t* __restrict__ qg, const half_t* __restrict__ kg,
        const half_t* __restrict__ vTg, const int* __restrict__ mask,
        const half_t* __restrict__ Wo, float* __restrict__ out) {
    __shared__ float bias[512];
    __shared__ int redc[8];
    __shared__ half_t Pb[8][32 * 36];        // per-wave P tile, row stride 36
    __shared__ half_t attO[32 * 136];        // [token_local][f], stride 136

    int bx = blockIdx.x;                     // 0..1023
    int bc = bx >> 4, qt = bx & 15;
    int tid = threadIdx.x;
    int w = tid >> 6, lane = tid & 63;
    int h = w;
    int bch = bc * 8 + h;
    int l31 = lane & 31, hf = lane >> 5;
    int l15 = lane & 15, quad = lane >> 4;

    const half_t* qh = qg + bch * 8192;
    const half_t* kh = kg + bch * 8192;
    const half_t* vh = vTg + bch * 8192;     // (d, n): d*512 + n

    // count unmasked keys for this bc (wave ballots -> block reduce)
    unsigned long long bal = __ballot(mask[bc * 512 + tid] == 0);
    if (lane == 0) redc[w] = __popcll(bal);
    __syncthreads();
    int cnt = redc[0] + redc[1] + redc[2] + redc[3]
            + redc[4] + redc[5] + redc[6] + redc[7];
    bias[tid] = (tid < cnt) ? C2 : -1.0e30f;
    __syncthreads();
    int NT = (cnt + 31) >> 5;

    int qbase = qt * 32;
    // Q B-fragment (32x32x16): lane holds q[qrow = l31][d = hf*8 + j]
    half8 qf = *(const half8*)(qh + (qbase + l31) * 16 + hf * 8);

    half8 ones;
#pragma unroll
    for (int j = 0; j < 8; ++j) ones[j] = (half_t)1.0f;

    floatx4 O[2], Os[2];
    O[0] = zero4(); O[1] = zero4();
    Os[0] = zero4(); Os[1] = zero4();
    const float4* b4 = (const float4*)bias;
    half_t* Pw = &Pb[w][0];

#pragma unroll 1
    for (int c = 0; c < NT; ++c) {
        // K A-fragment: A[slot = c*32 + l31][d = hf*8 + j]
        half8 kf = *(const half8*)(kh + (c * 32 + l31) * 16 + hf * 8);
        // V^T A-fragment for PV: A[d = l15][slot = c*32 + quad*8 + j]
        half8 vf = *(const half8*)(vh + l15 * 512 + c * 32 + quad * 8);
        float4 bv[4];
#pragma unroll
        for (int g = 0; g < 4; ++g) bv[g] = b4[c * 8 + hf + 2 * g];

        // S^T tile: D[slot][qrow], slot = 8*(r>>2) + 4*hf + (r&3), qrow-local = l31
        floatx16 S = __builtin_amdgcn_mfma_f32_32x32x16_f16(kf, qf, zero16(), 0, 0, 0);
#pragma unroll
        for (int g = 0; g < 4; ++g) {
            float p0 = pfun(S[4 * g + 0], bv[g].x);
            float p1 = pfun(S[4 * g + 1], bv[g].y);
            float p2 = pfun(S[4 * g + 2], bv[g].z);
            float p3 = pfun(S[4 * g + 3], bv[g].w);
            auto t0 = __builtin_amdgcn_cvt_pkrtz(p0, p1);   // __fp16 x2
            auto t1 = __builtin_amdgcn_cvt_pkrtz(p2, p3);
            half4 ph;
            ph[0] = (half_t)t0[0]; ph[1] = (half_t)t0[1];
            ph[2] = (half_t)t1[0]; ph[3] = (half_t)t1[1];
            *(half4*)(Pw + l31 * 36 + hf * 4 + g * 8) = ph;
        }
        // O^T += V^T * P^T ; Os += ones * P^T (row sums on MFMA pipe)
#pragma unroll
        for (int nt2 = 0; nt2 < 2; ++nt2) {
            half8 pb = *(const half8*)(Pw + (nt2 * 16 + l15) * 36 + quad * 8);
            O[nt2]  = __builtin_amdgcn_mfma_f32_16x16x32_f16(vf,   pb, O[nt2],  0, 0, 0);
            Os[nt2] = __builtin_amdgcn_mfma_f32_16x16x32_f16(ones, pb, Os[nt2], 0, 0, 0);
        }
    }

    // Normalize (lane-local: Os rows replicate the rowsum; O col = q = l15)
    // and write this head's 32x16 tile into attO[token_local][h*16 + ...].
#pragma unroll
    for (int nt = 0; nt < 2; ++nt) {
        float iv = __builtin_amdgcn_rcpf(Os[nt][0]);
        int qrl = nt * 16 + l15;             // token_local
        half4 ov;
        ov[0] = (half_t)(O[nt][0] * iv);
        ov[1] = (half_t)(O[nt][1] * iv);
        ov[2] = (half_t)(O[nt][2] * iv);
        ov[3] = (half_t)(O[nt][3] * iv);
        *(half4*)(attO + qrl * 136 + h * 16 + quad * 4) = ov;
    }
    __syncthreads();

    // ---- output projection: out[32 tokens][128 f] = attO @ Wo^T ----
    // wave w: tokens [tw*16, tw*16+16), f [fw*32, fw*32+32); 8 MFMAs.
    int tw = w & 1, fw = w >> 1;
    const half_t* xbase = attO + (tw * 16 + l15) * 136;
    floatx4 acc2[2];
    acc2[0] = zero4(); acc2[1] = zero4();
#pragma unroll
    for (int ks = 0; ks < 4; ++ks) {
        half8 xf = *(const half8*)(xbase + ks * 32 + quad * 8);
#pragma unroll
        for (int nt = 0; nt < 2; ++nt) {
            half8 wf = *(const half8*)(Wo + (fw * 32 + nt * 16 + l15) * 128 + ks * 32 + quad * 8);
            acc2[nt] = __builtin_amdgcn_mfma_f32_16x16x32_f16(wf, xf, acc2[nt], 0, 0, 0);
        }
    }
    // D[f = fw*32 + nt*16 + quad*4 + r][token = l15] -> coalesced float4
    int tokg = bc * 512 + qt * 32 + tw * 16 + l15;
#pragma unroll
    for (int nt = 0; nt < 2; ++nt) {
        float4 o;
        o.x = acc2[nt][0]; o.y = acc2[nt][1]; o.z = acc2[nt][2]; o.w = acc2[nt][3];
        *(float4*)(out + tokg * 128 + fw * 32 + nt * 16 + quad * 4) = o;
    }
}

extern "C" void kernel_launch(void* const* d_in, const int* in_sizes, int n_in,
                              void* d_out, int out_size, void* d_ws, size_t ws_size,
                              hipStream_t stream) {
    const float* Q    = (const float*)d_in[0];
    const float* K    = (const float*)d_in[1];
    const float* V    = (const float*)d_in[2];
    const int*   mask = (const int*)d_in[3];
    const float* Wq   = (const float*)d_in[4];
    const float* Wk   = (const float*)d_in[5];
    const float* Wv   = (const float*)d_in[6];
    const float* Wo   = (const float*)d_in[7];
    float* out = (float*)d_out;

    half_t* ws = (half_t*)d_ws;
    half_t* Who = ws + 49152;              // Wo fp16 (16384 halves)
    half_t* qw  = ws + 65536;              // each 4194304 halves
    half_t* kw  = qw + 4194304;            // COMPACTED keys (bc,h,slot,16)
    half_t* vw  = kw + 4194304;            // COMPACTED transposed (bc,h,d,slot)

    k_proj<<<dim3(512, 4), 256, 0, stream>>>(Q, K, V, mask, Wq, Wk, Wv, Wo,
                                             qw, kw, vw, Who);
    k_attn_out<<<1024, 512, 0, stream>>>(qw, kw, vw, mask, Who, out);
}